// Round 2
// baseline (187.428 us; speedup 1.0000x reference)
//
#include <hip/hip_runtime.h>
#include <hip/hip_bf16.h>

#define T_DIM 2048
#define N_DIM 128
#define K_DIM 256
#define C_DIM 40
#define SEG 256
#define SEGLEN 8      // T_DIM / SEG
#define GRP 8
#define SEGPERGRP 32  // SEG / GRP
#define TILES 16384   // (T_DIM*N_DIM)/16

typedef __attribute__((ext_vector_type(8))) short bf16x8;
typedef __attribute__((ext_vector_type(4))) float f32x4v;

__device__ __forceinline__ unsigned pack_bf16(float a, float b) {
    union { float f; unsigned u; } ua, ub;
    ua.f = a; ub.f = b;
    unsigned ra = (ua.u + 0x7FFFu + ((ua.u >> 16) & 1u)) >> 16;
    unsigned rb = (ub.u + 0x7FFFu + ((ub.u >> 16) & 1u)) >> 16;
    return (ra & 0xFFFFu) | (rb << 16);
}

__device__ __forceinline__ float fast_tanh(float v) {
    float e = __expf(2.f * v);
    return 1.f - 2.f / (e + 1.f);
}

// ---------------- Phase 1: y = 5*tanh(x W^T + b) ---------------------------
// W = MFMA A-operand, staged ONCE per block in swizzled LDS (24 KB).
// x = B-operand, loaded straight global -> VGPR -> bf16 (no LDS, no sync in loop).
// Each wave owns a 16-row tile per iteration; grid-stride over 16384 tiles.
__global__ __launch_bounds__(256) void k_gemm_tanh(
    const float* __restrict__ x, const float* __restrict__ W,
    const float* __restrict__ b, float* __restrict__ y)
{
    __shared__ __align__(16) unsigned shB[6144];  // 48 rows x 512B bf16, XOR-swizzled
    const int tid = threadIdx.x;

    // stage W (pad rows 40..47 with zeros), swizzle byte ^= (row&7)<<4
    for (int i = tid; i < 6144; i += 256) {
        int flat = i * 2;          // bf16 element index
        int r = flat >> 8;         // 0..47
        int k = flat & 255;        // even
        float v0 = 0.f, v1 = 0.f;
        if (r < C_DIM) { v0 = W[r * K_DIM + k]; v1 = W[r * K_DIM + k + 1]; }
        int byte = (k * 2) ^ ((r & 7) << 4);
        shB[(r * 512 + byte) >> 2] = pack_bf16(v0, v1);
    }
    __syncthreads();

    const int lane = tid & 63;
    const int wave = tid >> 6;
    const int lr = lane & 15;      // x-row within tile (B/N index)
    const int kg = lane >> 4;      // k-chunk group
    const int gw = blockIdx.x * 4 + wave;          // 4096 global waves
    const int bswz = (lr & 7) << 4;
    const char* cB = reinterpret_cast<const char*>(shB);

    float4 b0 = *reinterpret_cast<const float4*>(b + kg * 4);
    float4 b1 = *reinterpret_cast<const float4*>(b + 16 + kg * 4);
    float4 b2 = {0.f, 0.f, 0.f, 0.f};
    if (kg < 2) b2 = *reinterpret_cast<const float4*>(b + 32 + kg * 4);

    for (int tile = gw; tile < TILES; tile += 4096) {
        const size_t row = (size_t)tile * 16 + lr;
        const float* xr = x + row * K_DIM + kg * 8;

        f32x4v acc0 = {0.f, 0.f, 0.f, 0.f};
        f32x4v acc1 = {0.f, 0.f, 0.f, 0.f};
        f32x4v acc2 = {0.f, 0.f, 0.f, 0.f};

        #pragma unroll
        for (int kt = 0; kt < 8; ++kt) {
            float4 v0 = *reinterpret_cast<const float4*>(xr + kt * 32);
            float4 v1 = *reinterpret_cast<const float4*>(xr + kt * 32 + 4);
            union { bf16x8 v; unsigned u[4]; } xf;
            xf.u[0] = pack_bf16(v0.x, v0.y);
            xf.u[1] = pack_bf16(v0.z, v0.w);
            xf.u[2] = pack_bf16(v1.x, v1.y);
            xf.u[3] = pack_bf16(v1.z, v1.w);

            int kb2 = (kt * 32 + kg * 8) * 2;   // byte offset of k-chunk
            bf16x8 a0 = *reinterpret_cast<const bf16x8*>(cB + lr * 512 + (kb2 ^ bswz));
            bf16x8 a1 = *reinterpret_cast<const bf16x8*>(cB + (16 + lr) * 512 + (kb2 ^ bswz));
            bf16x8 a2 = *reinterpret_cast<const bf16x8*>(cB + (32 + lr) * 512 + (kb2 ^ bswz));
            acc0 = __builtin_amdgcn_mfma_f32_16x16x32_bf16(a0, xf.v, acc0, 0, 0, 0);
            acc1 = __builtin_amdgcn_mfma_f32_16x16x32_bf16(a1, xf.v, acc1, 0, 0, 0);
            acc2 = __builtin_amdgcn_mfma_f32_16x16x32_bf16(a2, xf.v, acc2, 0, 0, 0);
        }

        // D layout: x-row = lane&15, c = (lane>>4)*4 + reg
        float* yr = y + row * C_DIM;
        float4 o0, o1;
        o0.x = 5.f * fast_tanh(acc0[0] + b0.x);
        o0.y = 5.f * fast_tanh(acc0[1] + b0.y);
        o0.z = 5.f * fast_tanh(acc0[2] + b0.z);
        o0.w = 5.f * fast_tanh(acc0[3] + b0.w);
        o1.x = 5.f * fast_tanh(acc1[0] + b1.x);
        o1.y = 5.f * fast_tanh(acc1[1] + b1.y);
        o1.z = 5.f * fast_tanh(acc1[2] + b1.z);
        o1.w = 5.f * fast_tanh(acc1[3] + b1.w);
        *reinterpret_cast<float4*>(yr + kg * 4) = o0;
        *reinterpret_cast<float4*>(yr + 16 + kg * 4) = o1;
        if (kg < 2) {
            float4 o2;
            o2.x = 5.f * fast_tanh(acc2[0] + b2.x);
            o2.y = 5.f * fast_tanh(acc2[1] + b2.y);
            o2.z = 5.f * fast_tanh(acc2[2] + b2.z);
            o2.w = 5.f * fast_tanh(acc2[3] + b2.w);
            *reinterpret_cast<float4*>(yr + 32 + kg * 4) = o2;
        }
    }
}

// ---------------- Phase 2a: per-segment 8x8 transition matrices ------------
// ONE thread per (n, s): propagates the full 8x8 matrix -> 40 exps/step
// (shared across all 8 columns) instead of 320. Coalesced y reads.
__global__ __launch_bounds__(256) void k_seg(
    const float* __restrict__ y, float* __restrict__ segv, float* __restrict__ segl)
{
    int tid = blockIdx.x * 256 + threadIdx.x;   // 32768 total
    int n = tid & 127;
    int s = tid >> 7;

    float P[8][8];   // P[state j][init column c]
    #pragma unroll
    for (int j = 0; j < 8; ++j)
        #pragma unroll
        for (int c = 0; c < 8; ++c) P[j][c] = (j == c) ? 1.f : 0.f;

    for (int st = 0; st < SEGLEN; ++st) {
        int t = s * SEGLEN + st;
        const float* yr = y + ((size_t)t * N_DIM + n) * C_DIM;
        float e[40];
        #pragma unroll
        for (int i = 0; i < 10; ++i) {
            float4 v = reinterpret_cast<const float4*>(yr)[i];
            e[i * 4 + 0] = __expf(v.x);
            e[i * 4 + 1] = __expf(v.y);
            e[i * 4 + 2] = __expf(v.z);
            e[i * 4 + 3] = __expf(v.w);
        }
        #pragma unroll
        for (int c = 0; c < 8; ++c) {           // columns independent
            float np[8];
            #pragma unroll
            for (int j = 0; j < 4; ++j) {       // flip: all 8 sources
                float a = 0.f;
                #pragma unroll
                for (int i = 0; i < 8; ++i) a += P[i][c] * e[j * 8 + i];
                np[j] = a;
            }
            #pragma unroll
            for (int j = 0; j < 4; ++j)         // flop: 2 sources
                np[4 + j] = P[j][c] * e[32 + j] + P[4 + j][c] * e[36 + j];
            #pragma unroll
            for (int j = 0; j < 8; ++j) P[j][c] = np[j];
        }
    }
    #pragma unroll
    for (int c = 0; c < 8; ++c) {
        float sum = 0.f;
        #pragma unroll
        for (int j = 0; j < 8; ++j) sum += P[j][c];
        float inv = 1.f / sum;
        #pragma unroll
        for (int j = 0; j < 8; ++j)
            segv[(((size_t)s * 8 + c) * 8 + j) * N_DIM + n] = P[j][c] * inv;
        segl[((size_t)s * 8 + c) * N_DIM + n] = __logf(sum);
    }
}

// ---------------- Phase 2b: combine 32 segments per group ------------------
__global__ __launch_bounds__(256) void k_grp(
    const float* __restrict__ segv, const float* __restrict__ segl,
    float* __restrict__ grpv, float* __restrict__ grpl)
{
    int tid = blockIdx.x * 256 + threadIdx.x;  // 8192 total
    int n = tid & 127;
    int cc = (tid >> 7) & 7;
    int g = tid >> 10;

    float u[8];
    #pragma unroll
    for (int i = 0; i < 8; ++i) u[i] = (i == cc) ? 1.f : 0.f;
    float logacc = 0.f;

    for (int s = g * SEGPERGRP; s < (g + 1) * SEGPERGRP; ++s) {
        float l[8];
        #pragma unroll
        for (int i = 0; i < 8; ++i) l[i] = segl[((size_t)s * 8 + i) * N_DIM + n];
        float m = l[0];
        #pragma unroll
        for (int i = 1; i < 8; ++i) m = fmaxf(m, l[i]);
        float nu[8] = {0.f, 0.f, 0.f, 0.f, 0.f, 0.f, 0.f, 0.f};
        #pragma unroll
        for (int i = 0; i < 8; ++i) {
            float wi = u[i] * __expf(l[i] - m);
            #pragma unroll
            for (int j = 0; j < 8; ++j)
                nu[j] += wi * segv[(((size_t)s * 8 + i) * 8 + j) * N_DIM + n];
        }
        float sum = 0.f;
        #pragma unroll
        for (int j = 0; j < 8; ++j) sum += nu[j];
        float inv = 1.f / sum;
        #pragma unroll
        for (int j = 0; j < 8; ++j) u[j] = nu[j] * inv;
        logacc += m + __logf(sum);
    }
    #pragma unroll
    for (int j = 0; j < 8; ++j)
        grpv[(((size_t)g * 8 + cc) * 8 + j) * N_DIM + n] = u[j];
    grpl[((size_t)g * 8 + cc) * N_DIM + n] = logacc;
}

// ---------------- Phase 2c: fold 8 groups into logZ/T ----------------------
__global__ void k_fin(const float* __restrict__ grpv, const float* __restrict__ grpl,
                      float* __restrict__ lz)
{
    int n = threadIdx.x;  // 128
    float p[8] = {0.25f, 0.25f, 0.25f, 0.25f, 0.f, 0.f, 0.f, 0.f};
    float logZ = 1.3862943611198906f;  // log(4)

    for (int g = 0; g < GRP; ++g) {
        float l[8];
        #pragma unroll
        for (int i = 0; i < 8; ++i) l[i] = grpl[((size_t)g * 8 + i) * N_DIM + n];
        float m = l[0];
        #pragma unroll
        for (int i = 1; i < 8; ++i) m = fmaxf(m, l[i]);
        float nu[8] = {0.f, 0.f, 0.f, 0.f, 0.f, 0.f, 0.f, 0.f};
        #pragma unroll
        for (int i = 0; i < 8; ++i) {
            float wi = p[i] * __expf(l[i] - m);
            #pragma unroll
            for (int j = 0; j < 8; ++j)
                nu[j] += wi * grpv[(((size_t)g * 8 + i) * 8 + j) * N_DIM + n];
        }
        float sum = 0.f;
        #pragma unroll
        for (int j = 0; j < 8; ++j) sum += nu[j];
        float inv = 1.f / sum;
        #pragma unroll
        for (int j = 0; j < 8; ++j) p[j] = nu[j] * inv;
        logZ += m + __logf(sum);
    }
    lz[n] = logZ * (1.f / (float)T_DIM);
}

// ---------------- Phase 3: out -= logZ[n]/T (in place) ---------------------
__global__ __launch_bounds__(256) void k_sub(float* __restrict__ out,
                                             const float* __restrict__ lz)
{
    int i = blockIdx.x * 256 + threadIdx.x;   // float4 index; 2621440 total
    int n = (i / 10) & 127;
    float d = lz[n];
    float4* o = reinterpret_cast<float4*>(out) + i;
    float4 v = *o;
    v.x -= d; v.y -= d; v.z -= d; v.w -= d;
    *o = v;
}

extern "C" void kernel_launch(void* const* d_in, const int* in_sizes, int n_in,
                              void* d_out, int out_size, void* d_ws, size_t ws_size,
                              hipStream_t stream) {
    const float* x = (const float*)d_in[0];
    const float* W = (const float*)d_in[1];
    const float* b = (const float*)d_in[2];
    float* out = (float*)d_out;
    float* ws = (float*)d_ws;

    float* segv = ws;                  // SEG*8*8*128      = 2,097,152 f32
    float* segl = ws + 2097152;        // SEG*8*128        =   262,144 f32
    float* grpv = ws + 2359296;        // GRP*8*8*128      =    65,536 f32
    float* grpl = ws + 2424832;        // GRP*8*128        =     8,192 f32
    float* lz   = ws + 2433024;        // 128 f32

    k_gemm_tanh<<<1024, 256, 0, stream>>>(x, W, b, out);   // y -> d_out
    k_seg<<<128, 256, 0, stream>>>(out, segv, segl);
    k_grp<<<32, 256, 0, stream>>>(segv, segl, grpv, grpl);
    k_fin<<<1, 128, 0, stream>>>(grpv, grpl, lz);
    k_sub<<<10240, 256, 0, stream>>>(out, lz);
}

// Round 3
// 147.703 us; speedup vs baseline: 1.2689x; 1.2689x over previous
//
#include <hip/hip_runtime.h>
#include <hip/hip_bf16.h>

#define T_DIM 2048
#define N_DIM 128
#define K_DIM 256
#define C_DIM 40
#define SEG 256
#define SEGLEN 8      // T_DIM / SEG
#define GRP 8
#define SEGPERGRP 32  // SEG / GRP

typedef __attribute__((ext_vector_type(8))) short bf16x8;
typedef __attribute__((ext_vector_type(4))) float f32x4v;

__device__ __forceinline__ unsigned pack_bf16(float a, float b) {
    union { float f; unsigned u; } ua, ub;
    ua.f = a; ub.f = b;
    unsigned ra = (ua.u + 0x7FFFu + ((ua.u >> 16) & 1u)) >> 16;
    unsigned rb = (ub.u + 0x7FFFu + ((ub.u >> 16) & 1u)) >> 16;
    return (ra & 0xFFFFu) | (rb << 16);
}

__device__ __forceinline__ float fast_tanh(float v) {
    float e = __expf(2.f * v);
    return 1.f - 2.f / (e + 1.f);
}

// ---------------- Phase 1: y = 5*tanh(x W^T + b) ---------------------------
// W staged once (24KB swizzled bf16 LDS). Each WAVE independently streams
// 16-row x tiles via global_load_lds (f32, linear LDS dest, pre-swizzled
// global source) into a private 2x16KB double buffer. No barriers in loop;
// per-wave counted vmcnt keeps next tile's loads in flight during compute.
__global__ __launch_bounds__(256) void k_gemm_tanh(
    const float* __restrict__ x, const float* __restrict__ W,
    const float* __restrict__ b, float* __restrict__ y)
{
    __shared__ __align__(16) unsigned shW[6144];       // 48 rows x 512B bf16, swizzled
    __shared__ __align__(16) float shX[4][2][4096];    // per-wave dbuf: 16 rows x 256 f32

    const int tid = threadIdx.x;

    // stage W (pad rows 40..47 with zeros), swizzle byte ^= (row&7)<<4
    for (int i = tid; i < 6144; i += 256) {
        int flat = i * 2;
        int r = flat >> 8;
        int k = flat & 255;
        float v0 = 0.f, v1 = 0.f;
        if (r < C_DIM) { v0 = W[r * K_DIM + k]; v1 = W[r * K_DIM + k + 1]; }
        int byte = (k * 2) ^ ((r & 7) << 4);
        shW[(r * 512 + byte) >> 2] = pack_bf16(v0, v1);
    }
    __syncthreads();

    const int lane = tid & 63;
    const int wave = tid >> 6;
    const int lr = lane & 15;
    const int kg = lane >> 4;
    const int gw = blockIdx.x * 4 + wave;          // 1024 global waves, 16 tiles each
    const int bswz = (lr & 7) << 4;
    const char* cW = reinterpret_cast<const char*>(shW);

    float4 bia0 = *reinterpret_cast<const float4*>(b + kg * 4);
    float4 bia1 = *reinterpret_cast<const float4*>(b + 16 + kg * 4);
    float4 bia2 = {0.f, 0.f, 0.f, 0.f};
    if (kg < 2) bia2 = *reinterpret_cast<const float4*>(b + 32 + kg * 4);

    // issue 16 row-loads (1KB each) for tile -> per-wave buffer `buf`
    auto stage = [&](int tile, int buf) {
        const char* gbase = reinterpret_cast<const char*>(x) + (size_t)tile * 16 * 1024;
        float* lbase = &shX[wave][buf][0];
        #pragma unroll
        for (int r = 0; r < 16; ++r) {
            int srcoff = (lane * 16) ^ ((r & 7) << 4);   // inverse-swizzled source
            const void* gp = gbase + r * 1024 + srcoff;
            __builtin_amdgcn_global_load_lds(
                (const __attribute__((address_space(1))) void*)gp,
                (__attribute__((address_space(3))) void*)(lbase + r * 256),
                16, 0, 0);
        }
    };

    stage(gw * 16, 0);

    for (int tt = 0; tt < 16; ++tt) {
        int cur = tt & 1;
        if (tt < 15) stage(gw * 16 + tt + 1, cur ^ 1);
        __builtin_amdgcn_sched_barrier(0);
        if (tt < 15) asm volatile("s_waitcnt vmcnt(16)" ::: "memory");
        else         asm volatile("s_waitcnt vmcnt(0)" ::: "memory");
        __builtin_amdgcn_sched_barrier(0);

        const char* cX = reinterpret_cast<const char*>(&shX[wave][cur][0]);
        f32x4v acc0 = {0.f, 0.f, 0.f, 0.f};
        f32x4v acc1 = {0.f, 0.f, 0.f, 0.f};
        f32x4v acc2 = {0.f, 0.f, 0.f, 0.f};

        #pragma unroll
        for (int kt = 0; kt < 8; ++kt) {
            int g = kg * 32 + kt * 128;                 // logical byte in row
            float4 d0 = *reinterpret_cast<const float4*>(cX + lr * 1024 + (g ^ bswz));
            float4 d1 = *reinterpret_cast<const float4*>(cX + lr * 1024 + ((g + 16) ^ bswz));
            union { bf16x8 v; unsigned u[4]; } xf;
            xf.u[0] = pack_bf16(d0.x, d0.y);
            xf.u[1] = pack_bf16(d0.z, d0.w);
            xf.u[2] = pack_bf16(d1.x, d1.y);
            xf.u[3] = pack_bf16(d1.z, d1.w);

            int kb2 = kt * 64 + kg * 16;                // bf16 W byte offset
            bf16x8 a0 = *reinterpret_cast<const bf16x8*>(cW + lr * 512 + (kb2 ^ bswz));
            bf16x8 a1 = *reinterpret_cast<const bf16x8*>(cW + (16 + lr) * 512 + (kb2 ^ bswz));
            bf16x8 a2 = *reinterpret_cast<const bf16x8*>(cW + (32 + lr) * 512 + (kb2 ^ bswz));
            acc0 = __builtin_amdgcn_mfma_f32_16x16x32_bf16(a0, xf.v, acc0, 0, 0, 0);
            acc1 = __builtin_amdgcn_mfma_f32_16x16x32_bf16(a1, xf.v, acc1, 0, 0, 0);
            acc2 = __builtin_amdgcn_mfma_f32_16x16x32_bf16(a2, xf.v, acc2, 0, 0, 0);
        }

        // D layout: x-row = lane&15, c = (lane>>4)*4 + reg
        size_t row = (size_t)(gw * 16 + tt) * 16 + lr;
        float* yr = y + row * C_DIM;
        float4 o0, o1;
        o0.x = 5.f * fast_tanh(acc0[0] + bia0.x);
        o0.y = 5.f * fast_tanh(acc0[1] + bia0.y);
        o0.z = 5.f * fast_tanh(acc0[2] + bia0.z);
        o0.w = 5.f * fast_tanh(acc0[3] + bia0.w);
        o1.x = 5.f * fast_tanh(acc1[0] + bia1.x);
        o1.y = 5.f * fast_tanh(acc1[1] + bia1.y);
        o1.z = 5.f * fast_tanh(acc1[2] + bia1.z);
        o1.w = 5.f * fast_tanh(acc1[3] + bia1.w);
        *reinterpret_cast<float4*>(yr + kg * 4) = o0;
        *reinterpret_cast<float4*>(yr + 16 + kg * 4) = o1;
        if (kg < 2) {
            float4 o2;
            o2.x = 5.f * fast_tanh(acc2[0] + bia2.x);
            o2.y = 5.f * fast_tanh(acc2[1] + bia2.y);
            o2.z = 5.f * fast_tanh(acc2[2] + bia2.z);
            o2.w = 5.f * fast_tanh(acc2[3] + bia2.w);
            *reinterpret_cast<float4*>(yr + 32 + kg * 4) = o2;
        }
    }
}

// ---------------- Phase 2a: per-segment 8x8 transition matrices ------------
__global__ __launch_bounds__(128) void k_seg(
    const float* __restrict__ y, float* __restrict__ segv, float* __restrict__ segl)
{
    int tid = blockIdx.x * 128 + threadIdx.x;   // 32768 total
    int n = tid & 127;
    int s = tid >> 7;

    float P[8][8];   // P[state j][init column c]
    #pragma unroll
    for (int j = 0; j < 8; ++j)
        #pragma unroll
        for (int c = 0; c < 8; ++c) P[j][c] = (j == c) ? 1.f : 0.f;

    for (int st = 0; st < SEGLEN; ++st) {
        int t = s * SEGLEN + st;
        const float* yr = y + ((size_t)t * N_DIM + n) * C_DIM;
        float e[40];
        #pragma unroll
        for (int i = 0; i < 10; ++i) {
            float4 v = reinterpret_cast<const float4*>(yr)[i];
            e[i * 4 + 0] = __expf(v.x);
            e[i * 4 + 1] = __expf(v.y);
            e[i * 4 + 2] = __expf(v.z);
            e[i * 4 + 3] = __expf(v.w);
        }
        #pragma unroll
        for (int c = 0; c < 8; ++c) {
            float np[8];
            #pragma unroll
            for (int j = 0; j < 4; ++j) {       // flip: all 8 sources
                float a = 0.f;
                #pragma unroll
                for (int i = 0; i < 8; ++i) a += P[i][c] * e[j * 8 + i];
                np[j] = a;
            }
            #pragma unroll
            for (int j = 0; j < 4; ++j)         // flop: 2 sources
                np[4 + j] = P[j][c] * e[32 + j] + P[4 + j][c] * e[36 + j];
            #pragma unroll
            for (int j = 0; j < 8; ++j) P[j][c] = np[j];
        }
    }
    #pragma unroll
    for (int c = 0; c < 8; ++c) {
        float sum = 0.f;
        #pragma unroll
        for (int j = 0; j < 8; ++j) sum += P[j][c];
        float inv = 1.f / sum;
        #pragma unroll
        for (int j = 0; j < 8; ++j)
            segv[(((size_t)s * 8 + c) * 8 + j) * N_DIM + n] = P[j][c] * inv;
        segl[((size_t)s * 8 + c) * N_DIM + n] = __logf(sum);
    }
}

// ---------------- Phase 2b: combine 32 segments per group ------------------
__global__ __launch_bounds__(256) void k_grp(
    const float* __restrict__ segv, const float* __restrict__ segl,
    float* __restrict__ grpv, float* __restrict__ grpl)
{
    int tid = blockIdx.x * 256 + threadIdx.x;  // 8192 total
    int n = tid & 127;
    int cc = (tid >> 7) & 7;
    int g = tid >> 10;

    float u[8];
    #pragma unroll
    for (int i = 0; i < 8; ++i) u[i] = (i == cc) ? 1.f : 0.f;
    float logacc = 0.f;

    for (int s = g * SEGPERGRP; s < (g + 1) * SEGPERGRP; ++s) {
        float l[8];
        #pragma unroll
        for (int i = 0; i < 8; ++i) l[i] = segl[((size_t)s * 8 + i) * N_DIM + n];
        float m = l[0];
        #pragma unroll
        for (int i = 1; i < 8; ++i) m = fmaxf(m, l[i]);
        float nu[8] = {0.f, 0.f, 0.f, 0.f, 0.f, 0.f, 0.f, 0.f};
        #pragma unroll
        for (int i = 0; i < 8; ++i) {
            float wi = u[i] * __expf(l[i] - m);
            #pragma unroll
            for (int j = 0; j < 8; ++j)
                nu[j] += wi * segv[(((size_t)s * 8 + i) * 8 + j) * N_DIM + n];
        }
        float sum = 0.f;
        #pragma unroll
        for (int j = 0; j < 8; ++j) sum += nu[j];
        float inv = 1.f / sum;
        #pragma unroll
        for (int j = 0; j < 8; ++j) u[j] = nu[j] * inv;
        logacc += m + __logf(sum);
    }
    #pragma unroll
    for (int j = 0; j < 8; ++j)
        grpv[(((size_t)g * 8 + cc) * 8 + j) * N_DIM + n] = u[j];
    grpl[((size_t)g * 8 + cc) * N_DIM + n] = logacc;
}

// ---------------- Phase 2c: fold 8 groups into logZ/T ----------------------
__global__ void k_fin(const float* __restrict__ grpv, const float* __restrict__ grpl,
                      float* __restrict__ lz)
{
    int n = threadIdx.x;  // 128
    float p[8] = {0.25f, 0.25f, 0.25f, 0.25f, 0.f, 0.f, 0.f, 0.f};
    float logZ = 1.3862943611198906f;  // log(4)

    for (int g = 0; g < GRP; ++g) {
        float l[8];
        #pragma unroll
        for (int i = 0; i < 8; ++i) l[i] = grpl[((size_t)g * 8 + i) * N_DIM + n];
        float m = l[0];
        #pragma unroll
        for (int i = 1; i < 8; ++i) m = fmaxf(m, l[i]);
        float nu[8] = {0.f, 0.f, 0.f, 0.f, 0.f, 0.f, 0.f, 0.f};
        #pragma unroll
        for (int i = 0; i < 8; ++i) {
            float wi = p[i] * __expf(l[i] - m);
            #pragma unroll
            for (int j = 0; j < 8; ++j)
                nu[j] += wi * grpv[(((size_t)g * 8 + i) * 8 + j) * N_DIM + n];
        }
        float sum = 0.f;
        #pragma unroll
        for (int j = 0; j < 8; ++j) sum += nu[j];
        float inv = 1.f / sum;
        #pragma unroll
        for (int j = 0; j < 8; ++j) p[j] = nu[j] * inv;
        logZ += m + __logf(sum);
    }
    lz[n] = logZ * (1.f / (float)T_DIM);
}

// ---------------- Phase 3: out -= logZ[n]/T (in place) ---------------------
__global__ __launch_bounds__(256) void k_sub(float* __restrict__ out,
                                             const float* __restrict__ lz)
{
    int i = blockIdx.x * 256 + threadIdx.x;   // float4 index; 2621440 total
    int n = (i / 10) & 127;
    float d = lz[n];
    float4* o = reinterpret_cast<float4*>(out) + i;
    float4 v = *o;
    v.x -= d; v.y -= d; v.z -= d; v.w -= d;
    *o = v;
}

extern "C" void kernel_launch(void* const* d_in, const int* in_sizes, int n_in,
                              void* d_out, int out_size, void* d_ws, size_t ws_size,
                              hipStream_t stream) {
    const float* x = (const float*)d_in[0];
    const float* W = (const float*)d_in[1];
    const float* b = (const float*)d_in[2];
    float* out = (float*)d_out;
    float* ws = (float*)d_ws;

    float* segv = ws;                  // SEG*8*8*128      = 2,097,152 f32
    float* segl = ws + 2097152;        // SEG*8*128        =   262,144 f32
    float* grpv = ws + 2359296;        // GRP*8*8*128      =    65,536 f32
    float* grpl = ws + 2424832;        // GRP*8*128        =     8,192 f32
    float* lz   = ws + 2433024;        // 128 f32

    k_gemm_tanh<<<256, 256, 0, stream>>>(x, W, b, out);   // y -> d_out
    k_seg<<<256, 128, 0, stream>>>(out, segv, segl);
    k_grp<<<32, 256, 0, stream>>>(segv, segl, grpv, grpl);
    k_fin<<<1, 128, 0, stream>>>(grpv, grpl, lz);
    k_sub<<<10240, 256, 0, stream>>>(out, lz);
}